// Round 1
// baseline (436.635 us; speedup 1.0000x reference)
//
#include <hip/hip_runtime.h>

// y[u] = sum_{s,t,v} (x[st]*Wt[st]) * (Wr[st,u,v]*Rz[st,u,v] + Rc[st,u,v])
// N=80. Flat index of (st,u,v) = st*6400 + u*80 + v.
// Memory-bound: 3 x 163.84 MB streamed once -> ~78 us roofline @6.3 TB/s.

#define NN        80
#define NST       6400      // N*N st pairs
#define SLAB      6400      // floats per st slab (N*N)
#define CHUNKS    16        // st chunks
#define ST_PER_BLK 400      // NST / CHUNKS
#define ROWS_PER_IT 16      // st rows processed per iteration
#define ITERS     25        // ST_PER_BLK / ROWS_PER_IT
#define TPB       320       // 16 rows * 20 float4 per row

__global__ __launch_bounds__(TPB) void degree_pred_kernel(
    const float* __restrict__ x,
    const float* __restrict__ rz,
    const float* __restrict__ rc,
    const float* __restrict__ wt,
    const float* __restrict__ wr,
    float* __restrict__ y)
{
    const int u     = blockIdx.y;        // 0..79
    const int chunk = blockIdx.x;        // 0..15
    const int t     = (int)threadIdx.x;  // 0..319
    const int st0   = chunk * ST_PER_BLK;

    // layer2 = x * Wt for this block's contiguous st range (broadcast-reused)
    __shared__ float l2[ST_PER_BLK];
    for (int j = t; j < ST_PER_BLK; j += TPB)
        l2[j] = x[st0 + j] * wt[st0 + j];
    __syncthreads();

    const int row = t / 20;              // st offset within iteration (0..15)
    const int f4  = t % 20;              // float4 index within the 80-float v row

    const size_t ubase = (size_t)u * NN + (size_t)f4 * 4;

    float acc = 0.0f;
    #pragma unroll 5
    for (int it = 0; it < ITERS; ++it) {
        const int stl = it * ROWS_PER_IT + row;              // local st in [0,400)
        const size_t off = (size_t)(st0 + stl) * SLAB + ubase;
        const float4 a = *reinterpret_cast<const float4*>(wr + off);
        const float4 b = *reinterpret_cast<const float4*>(rz + off);
        const float4 c = *reinterpret_cast<const float4*>(rc + off);
        const float s = (a.x * b.x + c.x) + (a.y * b.y + c.y)
                      + (a.z * b.z + c.z) + (a.w * b.w + c.w);
        acc += l2[stl] * s;
    }

    // per-wave shuffle reduce (wave = 64 lanes), then one atomic per wave
    #pragma unroll
    for (int o = 32; o > 0; o >>= 1)
        acc += __shfl_down(acc, o, 64);
    if ((t & 63) == 0)
        atomicAdd(&y[u], acc);
}

extern "C" void kernel_launch(void* const* d_in, const int* in_sizes, int n_in,
                              void* d_out, int out_size, void* d_ws, size_t ws_size,
                              hipStream_t stream)
{
    const float* x  = (const float*)d_in[0];  // (80,80)
    const float* rz = (const float*)d_in[1];  // (80,80,80,80)
    const float* rc = (const float*)d_in[2];  // (80,80,80,80)
    const float* wt = (const float*)d_in[3];  // (80,80)
    const float* wr = (const float*)d_in[4];  // (80,80,80,80)
    float* y = (float*)d_out;                 // (80,)

    // d_out is re-poisoned to 0xAA before every timed launch -> zero it here.
    hipMemsetAsync(y, 0, (size_t)out_size * sizeof(float), stream);

    dim3 grid(CHUNKS, NN);
    degree_pred_kernel<<<grid, TPB, 0, stream>>>(x, rz, rc, wt, wr, y);
}